// Round 6
// baseline (260.548 us; speedup 1.0000x reference)
//
#include <hip/hip_runtime.h>
#include <hip/hip_bf16.h>
#include <stdint.h>

// Problem constants (B,T,C) = (4,4096,1024)
#define TT 4096
#define BB 4
#define CC 1024
#define MM (BB * TT)          // 16384 rows
#define NCHUNK 64             // scan chunks along T
#define CHUNK_T (TT / NCHUNK) // 64 steps per chunk
#define NCHAIN (BB * CC)      // 4096 independent scan chains

typedef float f32x4 __attribute__((ext_vector_type(4)));
typedef __bf16 bf16x8 __attribute__((ext_vector_type(8)));
typedef ushort us8 __attribute__((ext_vector_type(8)));

__device__ __forceinline__ float b2f(ushort u) {
  union { float f; uint32_t v; } x; x.v = ((uint32_t)u) << 16; return x.f;
}
__device__ __forceinline__ ushort f2b(float f) { // RNE fp32->bf16
  union { float f; uint32_t u; } x; x.f = f;
  uint32_t r = x.u + 0x7fffu + ((x.u >> 16) & 1u);
  return (ushort)(r >> 16);
}

// async global->LDS, 16B per lane. LDS dest must be uniform-base + lane*16.
__device__ __forceinline__ void async_copy16(const ushort* g, ushort* l) {
  __builtin_amdgcn_global_load_lds(
      (__attribute__((address_space(1))) void*)(g),
      (__attribute__((address_space(3))) void*)(l), 16, 0, 0);
}

// One kernel converts x, Wf, Wg, Wp to bf16. Sizes in float4 units:
// x: 4194304, each W: 262144. Total 4980736 = 19456 * 256 exactly.
// Wcat rows INTERLEAVED: row 2c = Wf[c], row 2c+1 = Wg[c], so the gates GEMM
// n-axis carries (f,g) channel pairs -> epilogue chunk-compose.
__global__ __launch_bounds__(256) void cvt_all(const float* __restrict__ x,
                                               const float* __restrict__ wf,
                                               const float* __restrict__ wg,
                                               const float* __restrict__ wp,
                                               ushort* __restrict__ xb,
                                               ushort* __restrict__ wcat,
                                               ushort* __restrict__ wpb) {
  const int i = blockIdx.x * 256 + threadIdx.x;
  const float* s; ushort* d; int off, dst;
  if (i < 4194304) {
    s = x; d = xb; off = i; dst = i;
  } else if (i < 4456448) {
    s = wf; d = wcat; off = i - 4194304;
    dst = ((off >> 8) << 9) + (off & 255);        // row c -> row 2c
  } else if (i < 4718592) {
    s = wg; d = wcat; off = i - 4456448;
    dst = ((off >> 8) << 9) + 256 + (off & 255);  // row c -> row 2c+1
  } else {
    s = wp; d = wpb; off = i - 4718592; dst = off;
  }
  float4 v = ((const float4*)s)[off];
  ushort4 o;
  o.x = f2b(v.x); o.y = f2b(v.y); o.z = f2b(v.z); o.w = f2b(v.w);
  ((ushort4*)d)[dst] = o;
}

// ===========================================================================
// GEMM core: R9 8-phase, 4-slot ring, counted vmcnt -- PARKED (R7/R8/R9 all
// ~83-85 us / 33% MfmaUtil; schedule knob exhausted at this tile config).
// MODE-1 epilogue: R11 LDS-slab chunk-compose (proven, 85.0 us).
// R12 changes are in scan_pass3 ONLY (occupancy 1 -> 2 waves/SIMD).
// ===========================================================================

#define RDA(sl, ih)                                                       \
  _Pragma("unroll") for (int i_ = 0; i_ < 4; ++i_)                        \
      af[i_] = *(const bf16x8*)(rA + (sl) * 8192 + (ih) * 2048 + i_ * 512);

#define RDB(sl)                                                           \
  _Pragma("unroll") for (int j_ = 0; j_ < 4; ++j_)                        \
      bfr[j_] = *(const bf16x8*)(rB + (sl) * 8192 + j_ * 512);

#define MFMA16(ih)                                                        \
  __builtin_amdgcn_s_setprio(1);                                          \
  _Pragma("unroll") for (int i_ = 0; i_ < 4; ++i_)                        \
  _Pragma("unroll") for (int j_ = 0; j_ < 4; ++j_)                        \
      acc[(ih) * 4 + i_][j_] = __builtin_amdgcn_mfma_f32_16x16x32_bf16(   \
          bfr[j_], af[i_], acc[(ih) * 4 + i_][j_], 0, 0, 0);              \
  __builtin_amdgcn_s_setprio(0)

#define MIDBAR()                                                          \
  __builtin_amdgcn_s_barrier();                                           \
  asm volatile("s_waitcnt lgkmcnt(0)" ::: "memory");                      \
  __builtin_amdgcn_sched_barrier(0)

#define ENDBAR()                                                          \
  __builtin_amdgcn_s_barrier();                                           \
  __builtin_amdgcn_sched_barrier(0)

#define CK4() asm volatile("s_waitcnt vmcnt(4)" ::: "memory")
#define CK0() asm volatile("s_waitcnt vmcnt(0)" ::: "memory")

// One K-tile (BK=64) = 4 phases; stages the 4 pieces of the NEXT tile.
#define TILE(S0, S1, NS0, NS1, KN)                                        \
  RDA(S0, 0); RDB(S0); stageA(NS0, (KN));      MIDBAR(); MFMA16(0);        ENDBAR(); \
  RDA(S0, 1);          stageB(NS0, (KN));      MIDBAR(); MFMA16(1); CK4(); ENDBAR(); \
  RDA(S1, 0); RDB(S1); stageA(NS1, (KN) + 32); MIDBAR(); MFMA16(0);        ENDBAR(); \
  RDA(S1, 1);          stageB(NS1, (KN) + 32); MIDBAR(); MFMA16(1); CK4(); ENDBAR();

template <int MODE>
__global__ __launch_bounds__(512, 2) void gemm_bt(const ushort* __restrict__ A,
                                                  const ushort* __restrict__ Bw,
                                                  float* __restrict__ outF,
                                                  ushort* __restrict__ outB,
                                                  float* __restrict__ cA2,
                                                  float* __restrict__ cB2, int N) {
  constexpr int K = CC; // 1024 -> 16 K-tiles of 64 (32 K-half pieces)
  __shared__ __align__(16) ushort sA[4 * 256 * 32]; // 4 x 16 KB ring = 64 KB
  __shared__ __align__(16) ushort sB[4 * 256 * 32]; // 64 KB

  const int tid = threadIdx.x;
  const int lane = tid & 63;
  const int w = tid >> 6;  // 0..7
  const int wm = w >> 2;   // 0..1: 128-row M half
  const int wn = w & 3;    // 0..3: 64-col N quarter

  // XCD-aware bijective swizzle (nwg = 512 or 256, both % 8 == 0)
  const int nbx = N >> 8;
  const int cpx = (int)gridDim.x >> 3;
  const int bid = blockIdx.x;
  const int wg = (bid & 7) * cpx + (bid >> 3);
  const long n0 = (long)(wg % nbx) << 8;
  const long m0 = (long)(wg / nbx) << 8;

  // ---- staging: piece = 256 rows x 64 B. Wave w covers rows w*16..+15 (hb0)
  // and 128+w*16..+15 (hb1), one gload_lds (1 KB) each. lane -> row lane>>2,
  // LDS octet lane&3; global octet pre-swizzled (lane&3)^((lane>>3)&3).
  const int srow = lane >> 2;
  const int goct = (lane & 3) ^ ((lane >> 3) & 3);
  const ushort* gA0 = A + (m0 + w * 16 + srow) * K + goct * 8;
  const ushort* gB0 = Bw + (n0 + w * 16 + srow) * K + goct * 8;
  const ushort* gA1 = gA0 + 128 * (long)K;
  const ushort* gB1 = gB0 + 128 * (long)K;
  ushort* dA0 = &sA[w * 512 + lane * 8];
  ushort* dA1 = dA0 + 4096; // rows +128 within piece
  ushort* dB0 = &sB[w * 512 + lane * 8];
  ushort* dB1 = dB0 + 4096;

  auto stageA = [&](int slot, int koff) {
    async_copy16(gA0 + koff, dA0 + slot * 8192);
    async_copy16(gA1 + koff, dA1 + slot * 8192);
  };
  auto stageB = [&](int slot, int koff) {
    async_copy16(gB0 + koff, dB0 + slot * 8192);
    async_copy16(gB1 + koff, dB1 + slot * 8192);
  };

  // ---- fragment reads: row r, octet slot kq ^ ((r>>1)&3)  (R7 0-conflict)
  const int rlo = lane & 15;
  const int kq = lane >> 4;
  const int oslot = kq ^ ((rlo >> 1) & 3);
  const ushort* rA = &sA[(wm * 128 + rlo) * 32 + oslot * 8]; // +sl*8192+ih*2048+i*512
  const ushort* rB = &sB[(wn * 64 + rlo) * 32 + oslot * 8];  // +sl*8192+j*512

  f32x4 acc[8][4];
#pragma unroll
  for (int i = 0; i < 8; ++i)
#pragma unroll
    for (int j = 0; j < 4; ++j) acc[i][j] = (f32x4){0.f, 0.f, 0.f, 0.f};

  bf16x8 af[4], bfr[4];

  // prologue: stage tile 0's 4 pieces; confirm As0,Bs0 (leave As1,Bs1 flying)
  stageA(0, 0);
  stageB(0, 0);
  stageA(1, 32);
  stageB(1, 32);
  CK4();
  ENDBAR();

  // main loop: tiles 0..13 (2 per iter; slot pattern period 2 -> constants)
  for (int t2 = 0; t2 < 7; ++t2) {
    const int kn = t2 * 128 + 64; // stage koff for tile 2*t2+1
    TILE(0, 1, 2, 3, kn);         // even tile: reads slots 0,1; stages 2,3
    TILE(2, 3, 0, 1, kn + 64);    // odd tile:  reads slots 2,3; stages 0,1
  }
  // tile 14 (even): stages tile 15 (slots 2,3; koff 960/992)
  TILE(0, 1, 2, 3, 960);
  // tile 15 (odd, slots 2,3): no stages; drain only here
  RDA(2, 0); RDB(2); MIDBAR(); MFMA16(0); ENDBAR();
  RDA(2, 1);         MIDBAR(); MFMA16(1); CK0(); ENDBAR();
  RDA(3, 0); RDB(3); MIDBAR(); MFMA16(0); ENDBAR();
  RDA(3, 1);         MIDBAR(); MFMA16(1);

  // Swapped C/D mapping (R3-verified): m = lane&15 axis, n = (lane>>4)*4 + reg.
  const int mloc = lane & 15;
  const int nq = (lane >> 4) * 4;

  if (MODE == 0) {
#pragma unroll
    for (int i = 0; i < 8; ++i) {
      const long m = m0 + wm * 128 + i * 16 + mloc;
#pragma unroll
      for (int j = 0; j < 4; ++j) {
        const long nb = n0 + wn * 64 + j * 16 + nq;
        *(f32x4*)(outF + m * N + nb) = acc[i][j];
      }
    }
  } else {
    // ---- fused activation + P store + chunk compose (LDS-slab version) ----
    const long bIdx = m0 >> 12;                   // batch
    const int t0 = (int)(m0 & 4095) + wm * 128;   // wave t base (mult of 128)
    const long chb = (n0 >> 1) + wn * 32;         // wave channel base
    // per-wave PRIVATE 16 KB slab: waves 0-3 carve sA, waves 4-7 carve sB.
    float* slab = (float*)((w < 4) ? &sA[w * 8192] : &sB[(w - 4) * 8192]);
    // one block barrier: every wave's GEMM ds_reads are lgkm-drained before
    // its last MFMA, so after this barrier the ring is safely reusable.
    __builtin_amdgcn_s_barrier();
    __builtin_amdgcn_sched_barrier(0);

    const int chl = lane & 31;  // read-phase: local channel
    const int thf = lane >> 5;  // read-phase: t-half of the 64-t chunk
#pragma unroll
    for (int rd = 0; rd < 2; ++rd) {              // i-halves = 64-t chunks
      // write phase: 4 i x 4 j frags x 2 ch-pairs = 32 float2 stores
#pragma unroll
      for (int ii = 0; ii < 4; ++ii) {
        const int i = rd * 4 + ii;
        const long m = m0 + wm * 128 + i * 16 + mloc;
        const int tl = ii * 16 + mloc;            // t within chunk, 0..63
#pragma unroll
        for (int j = 0; j < 4; ++j) {
          const long nb = n0 + wn * 64 + j * 16 + nq;
          const f32x4 v = acc[i][j];
          // parity activation: even n = f (sigmoid), odd n = g (tanh)
          float f0 = __builtin_amdgcn_rcpf(1.f + __expf(-v[0]));
          float g0 = fmaf(-2.f, __builtin_amdgcn_rcpf(1.f + __expf(2.f * v[1])), 1.f);
          float f1 = __builtin_amdgcn_rcpf(1.f + __expf(-v[2]));
          float g1 = fmaf(-2.f, __builtin_amdgcn_rcpf(1.f + __expf(2.f * v[3])), 1.f);
          ushort4 o;
          o.x = f2b(f0); o.y = f2b(g0); o.z = f2b(f1); o.w = f2b(g1);
          *(ushort4*)(outB + m * (long)N + nb) = o;
          // rounded values (== what pass3 reads back from P)
          const float fr0 = b2f(o.x), gr0 = b2f(o.y);
          const float fr1 = b2f(o.z), gr1 = b2f(o.w);
          const int c0 = j * 8 + (nq >> 1);       // local ch of (v0,v1)
          float2 p0; p0.x = fr0; p0.y = (1.f - fr0) * gr0;
          float2 p1; p1.x = fr1; p1.y = (1.f - fr1) * gr1;
          // slab[ch][slot] with slot = t ^ ch (bank-spread involution)
          *(float2*)(slab + (c0 * 64 + (tl ^ c0)) * 2) = p0;
          *(float2*)(slab + ((c0 + 1) * 64 + (tl ^ (c0 + 1))) * 2) = p1;
        }
      }
      // wave-private slab -> wave-local wait only (no block barrier)
      asm volatile("s_waitcnt lgkmcnt(0)" ::: "memory");
      __builtin_amdgcn_sched_barrier(0);
      // read+compose: lane = (ch=chl, t-half=thf), 32 ordered serial steps
      float Av = 1.f, Bv = 0.f;
#pragma unroll
      for (int s = 0; s < 32; ++s) {
        const int t = thf * 32 + s;
        const float2 ab = *(const float2*)(slab + (chl * 64 + (t ^ chl)) * 2);
        Bv = fmaf(ab.x, Bv, ab.y);
        Av *= ab.x;
      }
      // ordered merge across t-halves: full = hi o lo
      const float Ao = __shfl_xor(Av, 32);
      const float Bo = __shfl_xor(Bv, 32);
      const float Af = (thf == 0) ? Ao * Av : Av * Ao;
      const float Bf = (thf == 0) ? fmaf(Ao, Bv, Bo) : fmaf(Av, Bo, Bv);
      if (thf == 0) {
        const int gchunk = (t0 >> 6) + rd;        // 0..63
        const long i0 = (bIdx * CC + chb + chl) * 64 + gchunk;
        cA2[i0] = Af;
        cB2[i0] = Bf;
      }
      if (rd == 0) { // reads done before next round overwrites the slab
        asm volatile("s_waitcnt lgkmcnt(0)" ::: "memory");
        __builtin_amdgcn_sched_barrier(0);
      }
    }
  }
}

// ===== Scan: pass1 fused into gates epilogue; pass2 wave-parallel =====
// cA2/cB2/h2 layout: [chain][64] chain-major (coalesced per-wave access).
__global__ __launch_bounds__(256) void scan_pass2(const float* __restrict__ cA2,
                                                  const float* __restrict__ cB2,
                                                  float* __restrict__ h2) {
  const int gid = blockIdx.x * 256 + threadIdx.x;
  const int chain = gid >> 6; // one wave per chain (4096 chains)
  const int lane = threadIdx.x & 63;
  float Av = cA2[chain * 64 + lane];
  float Bv = cB2[chain * 64 + lane];
  // inclusive ordered scan over 64 chunk factors
#pragma unroll
  for (int m = 1; m < 64; m <<= 1) {
    const float Ao = __shfl_up(Av, m);
    const float Bo = __shfl_up(Bv, m);
    if (lane >= m) { Bv = fmaf(Av, Bo, Bv); Av = Av * Ao; }
  }
  // exclusive carry: h before chunk `lane`
  const float Bx = __shfl_up(Bv, 1);
  h2[chain * 64 + lane] = (lane == 0) ? 0.f : Bx;
}

// pass3 (R12): 2 chains/thread (was 4) -> 2048 threads, grid (8,64) = 512
// blocks = 2 waves/SIMD (was 1). Latency-bound dependent-FMA loop doubles
// its TLP; same bytes, same per-chain math order (absmax bit-identical).
// Loads ushort4 (f,g,f,g interleaved, 8 B/lane coalesced); stores ushort2.
__global__ __launch_bounds__(256) void scan_pass3(const ushort* __restrict__ P,
                                                  const float* __restrict__ h2,
                                                  ushort* __restrict__ H) {
  const int pc = blockIdx.x * 256 + threadIdx.x;  // 0..2047: chain pair
  const int chunk = blockIdx.y;                   // 0..63
  const int b = pc >> 9;                          // 512 pairs per batch
  const int c2 = (pc & 511) * 2;                  // channel base (2 chains)
  float h0 = h2[(b * CC + c2) * 64 + chunk];
  float h1 = h2[(b * CC + c2 + 1) * 64 + chunk];
  const ushort4* p =
      (const ushort4*)(P + (size_t)(b * TT + chunk * CHUNK_T) * (2 * CC) + c2 * 2);
  ushort2* hp = (ushort2*)(H + (size_t)(b * TT + chunk * CHUNK_T) * CC + c2);
#pragma unroll 8
  for (int i = 0; i < CHUNK_T; ++i) {
    const ushort4 v = p[0];
    p += 2 * CC / 4;
    const float f0 = b2f(v.x), g0 = b2f(v.y);
    const float f1 = b2f(v.z), g1 = b2f(v.w);
    h0 = fmaf(f0, h0, (1.f - f0) * g0);
    h1 = fmaf(f1, h1, (1.f - f1) * g1);
    ushort2 o;
    o.x = f2b(h0);
    o.y = f2b(h1);
    *hp = o;
    hp += CC / 2;
  }
}

extern "C" void kernel_launch(void* const* d_in, const int* in_sizes, int n_in,
                              void* d_out, int out_size, void* d_ws, size_t ws_size,
                              hipStream_t stream) {
  const float* x  = (const float*)d_in[0];
  const float* Wf = (const float*)d_in[1];
  const float* Wg = (const float*)d_in[2];
  const float* Wp = (const float*)d_in[3];

  // workspace layout (bytes) -- identical footprint to R6-R11.
  // H aliases xb (xb dead after gates GEMM, stream-ordered). cA2/cB2/h2 live
  // in the tail (written during gates epilogue -> must NOT overlay Wcat).
  char* ws = (char*)d_ws;
  ushort* xb   = (ushort*)(ws);                                  // 33554432 B
  ushort* Hb   = xb;                                             // alias
  ushort* Wcat = (ushort*)(ws + 33554432);                       //  4194304 B (interleaved Wf/Wg)
  ushort* Wpb  = (ushort*)(ws + 33554432 + 4194304);             //  2097152 B
  ushort* P    = (ushort*)(ws + 33554432 + 4194304 + 2097152);   // 67108864 B (f,g interleaved bf16)
  char* tail   = ws + 33554432 + 4194304 + 2097152 + 67108864;
  float* cA2   = (float*)(tail);                                 // 1 MiB (4096*64*4)
  float* cB2   = (float*)(tail + 1048576);                       // 1 MiB
  float* h2    = (float*)(tail + 2097152);                       // 1 MiB
  (void)ws_size; (void)in_sizes; (void)n_in; (void)out_size;

  // 1) all fp32 -> bf16 conversions in one launch (Wcat interleaved)
  cvt_all<<<19456, 256, 0, stream>>>(x, Wf, Wg, Wp, xb, Wcat, Wpb);

  // 2) gates GEMM + fused activation + chunk composition
  gemm_bt<1><<<512, 512, 0, stream>>>(xb, Wcat, nullptr, P, cA2, cB2, 2 * CC);

  // 3) carry scan (wave-parallel) + fixup sweep (2 waves/SIMD)
  scan_pass2<<<NCHAIN * 64 / 256, 256, 0, stream>>>(cA2, cB2, h2);
  dim3 gs(NCHAIN / 2 / 256, NCHUNK);
  scan_pass3<<<gs, 256, 0, stream>>>(P, h2, Hb);

  // 4) projection GEMM: out = H @ Wp^T (fp32), 256x256 tiles -> 256 blocks
  gemm_bt<0><<<256, 512, 0, stream>>>(Hb, Wpb, (float*)d_out, nullptr, nullptr, nullptr, CC);
}